// Round 1
// baseline (189.024 us; speedup 1.0000x reference)
//
#include <hip/hip_runtime.h>
#include <hip/hip_bf16.h>

#define NG 512
#define IMG_H 192
#define IMG_W 192
#define GF 10   // floats per gaussian in sorted table: u,v,A,B,C,op,beta,r,g,b

// ---------------- Kernel 1: per-gaussian preprocess + depth sort ----------------
__global__ __launch_bounds__(NG) void preprocess_kernel(
    const float* __restrict__ means, const float* __restrict__ quats,
    const float* __restrict__ scales, const float* __restrict__ opac,
    const float* __restrict__ colors, const float* __restrict__ betas,
    const float* __restrict__ vm, const float* __restrict__ Ks,
    float* __restrict__ ws)
{
    __shared__ float zsh[NG];
    const int g = threadIdx.x;

    // viewmat (row-major 4x4) and K (row-major 3x3)
    const float Rw[3][3] = {{vm[0], vm[1], vm[2]},
                            {vm[4], vm[5], vm[6]},
                            {vm[8], vm[9], vm[10]}};
    const float tw[3] = {vm[3], vm[7], vm[11]};
    const float fx = Ks[0], cx = Ks[2], fy = Ks[4], cy = Ks[5];

    const float mx = means[g*3+0], my = means[g*3+1], mz = means[g*3+2];
    const float px = Rw[0][0]*mx + Rw[0][1]*my + Rw[0][2]*mz + tw[0];
    const float py = Rw[1][0]*mx + Rw[1][1]*my + Rw[1][2]*mz + tw[1];
    const float pz = Rw[2][0]*mx + Rw[2][1]*my + Rw[2][2]*mz + tw[2];
    zsh[g] = pz;

    // quaternion -> rotation
    float qw = quats[g*4+0], qx = quats[g*4+1], qy = quats[g*4+2], qz = quats[g*4+3];
    const float qn = 1.0f / sqrtf(qw*qw + qx*qx + qy*qy + qz*qz);
    qw *= qn; qx *= qn; qy *= qn; qz *= qn;
    float Rq[3][3];
    Rq[0][0] = 1.f - 2.f*(qy*qy + qz*qz); Rq[0][1] = 2.f*(qx*qy - qw*qz); Rq[0][2] = 2.f*(qx*qz + qw*qy);
    Rq[1][0] = 2.f*(qx*qy + qw*qz); Rq[1][1] = 1.f - 2.f*(qx*qx + qz*qz); Rq[1][2] = 2.f*(qy*qz - qw*qx);
    Rq[2][0] = 2.f*(qx*qz - qw*qy); Rq[2][1] = 2.f*(qy*qz + qw*qx); Rq[2][2] = 1.f - 2.f*(qx*qx + qy*qy);

    const float e0 = expf(scales[g*3+0]);
    const float e1 = expf(scales[g*3+1]);
    const float e2 = expf(scales[g*3+2]);

    // M = Rq * diag(exp(s)) ; cov3d = M M^T
    float M[3][3];
    #pragma unroll
    for (int i = 0; i < 3; i++) { M[i][0] = Rq[i][0]*e0; M[i][1] = Rq[i][1]*e1; M[i][2] = Rq[i][2]*e2; }
    float c3[3][3];
    #pragma unroll
    for (int i = 0; i < 3; i++)
        #pragma unroll
        for (int k = 0; k < 3; k++)
            c3[i][k] = M[i][0]*M[k][0] + M[i][1]*M[k][1] + M[i][2]*M[k][2];

    // covc = Rw c3 Rw^T
    float tmp[3][3];
    #pragma unroll
    for (int i = 0; i < 3; i++)
        #pragma unroll
        for (int k = 0; k < 3; k++)
            tmp[i][k] = Rw[i][0]*c3[0][k] + Rw[i][1]*c3[1][k] + Rw[i][2]*c3[2][k];
    float S[3][3];
    #pragma unroll
    for (int i = 0; i < 3; i++)
        #pragma unroll
        for (int l = 0; l < 3; l++)
            S[i][l] = tmp[i][0]*Rw[l][0] + tmp[i][1]*Rw[l][1] + tmp[i][2]*Rw[l][2];

    const float tz = fmaxf(pz, 0.01f);
    const float z1 = 1.0f / tz;
    // J rows: J0 = (j0, 0, j2), J1 = (0, j1, j3)
    const float j0 = fx*z1, j2 = -fx*px*z1*z1;
    const float j1 = fy*z1, j3 = -fy*py*z1*z1;

    const float cov00 = j0*j0*S[0][0] + 2.f*j0*j2*S[0][2] + j2*j2*S[2][2];
    const float cov01 = j0*j1*S[0][1] + j0*j3*S[0][2] + j2*j1*S[1][2] + j2*j3*S[2][2];
    const float cov11 = j1*j1*S[1][1] + 2.f*j1*j3*S[1][2] + j3*j3*S[2][2];

    const float a = cov00 + 0.3f;
    const float b = cov01;
    const float c = cov11 + 0.3f;
    const float det = a*c - b*b;
    const float u = fx*px*z1 + cx;
    const float v = fy*py*z1 + cy;
    const bool valid = (pz > 0.01f) && (det > 1e-6f);
    const float inv_det = 1.0f / fmaxf(det, 1e-6f);
    const float Ac = c * inv_det;
    const float Bc = -b * inv_det;
    const float Cc = a * inv_det;
    float op = 1.0f / (1.0f + expf(-opac[g]));
    if (!valid) op = 0.0f;   // zero opacity == zero alpha == invalid gaussian

    __syncthreads();
    // stable rank by depth (matches jnp.argsort stable semantics)
    int rank = 0;
    #pragma unroll 8
    for (int j = 0; j < NG; j++) {
        const float zj = zsh[j];
        rank += (zj < pz) || (zj == pz && j < g);
    }

    float* dst = ws + rank * GF;
    dst[0] = u;  dst[1] = v;  dst[2] = Ac; dst[3] = Bc; dst[4] = Cc;
    dst[5] = op; dst[6] = betas[g];
    dst[7] = colors[g*3+0]; dst[8] = colors[g*3+1]; dst[9] = colors[g*3+2];
}

// ---------------- Kernel 2: per-pixel front-to-back compositing ----------------
__global__ __launch_bounds__(256) void render_kernel(
    const float* __restrict__ ws, float* __restrict__ out)
{
    __shared__ float gs[NG * GF];
    for (int i = threadIdx.x; i < NG * GF; i += 256) gs[i] = ws[i];
    __syncthreads();

    const int pix = blockIdx.x * 256 + threadIdx.x;
    const int x = pix % IMG_W;
    const int y = pix / IMG_W;
    const float fxp = (float)x + 0.5f;
    const float fyp = (float)y + 0.5f;

    float T = 1.0f, cr = 0.0f, cg = 0.0f, cb = 0.0f, ac = 0.0f;
    for (int i = 0; i < NG; i++) {
        const float* gp = gs + i * GF;           // all lanes same addr -> LDS broadcast
        const float dx = fxp - gp[0];
        const float dy = fyp - gp[1];
        float sigma = 0.5f * (gp[2]*dx*dx + gp[4]*dy*dy) + gp[3]*dx*dy;
        sigma = fmaxf(sigma, 1e-8f);
        const float bt = gp[6];
        const float se = (bt == 1.0f) ? sigma : powf(sigma, bt);
        float alpha = gp[5] * expf(-se);
        alpha = fminf(alpha, 0.999f);
        if (!(alpha > (1.0f/255.0f))) alpha = 0.0f;
        const float w = alpha * T;
        cr += w * gp[7]; cg += w * gp[8]; cb += w * gp[9];
        ac += w;
        T *= 1.0f - alpha;
        if (T < 1e-7f) break;   // remaining contribution < 1e-7 << threshold
    }

    const int base = (y * IMG_W + x) * 3;
    out[base + 0] = cr;
    out[base + 1] = cg;
    out[base + 2] = cb;
    out[IMG_H * IMG_W * 3 + y * IMG_W + x] = ac;
}

extern "C" void kernel_launch(void* const* d_in, const int* in_sizes, int n_in,
                              void* d_out, int out_size, void* d_ws, size_t ws_size,
                              hipStream_t stream) {
    const float* means  = (const float*)d_in[0];
    const float* quats  = (const float*)d_in[1];
    const float* scales = (const float*)d_in[2];
    const float* opac   = (const float*)d_in[3];
    const float* colors = (const float*)d_in[4];
    const float* betas  = (const float*)d_in[5];
    const float* vm     = (const float*)d_in[6];
    const float* Ks     = (const float*)d_in[7];
    float* ws  = (float*)d_ws;
    float* out = (float*)d_out;

    preprocess_kernel<<<1, NG, 0, stream>>>(means, quats, scales, opac, colors, betas, vm, Ks, ws);
    render_kernel<<<(IMG_H * IMG_W) / 256, 256, 0, stream>>>(ws, out);
}

// Round 2
// 85.490 us; speedup vs baseline: 2.2111x; 2.2111x over previous
//
#include <hip/hip_runtime.h>
#include <hip/hip_bf16.h>

#define NG 512
#define IMG_H 192
#define IMG_W 192
#define NPIX (IMG_H * IMG_W)
#define GF 10   // floats per gaussian: u,v,A,B,C,op,beta,r,g,b
#define NCHUNK 8

// ---------------- Kernel 1: per-gaussian preprocess + depth sort ----------------
__global__ __launch_bounds__(NG) void preprocess_kernel(
    const float* __restrict__ means, const float* __restrict__ quats,
    const float* __restrict__ scales, const float* __restrict__ opac,
    const float* __restrict__ colors, const float* __restrict__ betas,
    const float* __restrict__ vm, const float* __restrict__ Ks,
    float* __restrict__ ws)
{
    __shared__ float zsh[NG];
    const int g = threadIdx.x;

    const float Rw[3][3] = {{vm[0], vm[1], vm[2]},
                            {vm[4], vm[5], vm[6]},
                            {vm[8], vm[9], vm[10]}};
    const float tw[3] = {vm[3], vm[7], vm[11]};
    const float fx = Ks[0], cx = Ks[2], fy = Ks[4], cy = Ks[5];

    const float mx = means[g*3+0], my = means[g*3+1], mz = means[g*3+2];
    const float px = Rw[0][0]*mx + Rw[0][1]*my + Rw[0][2]*mz + tw[0];
    const float py = Rw[1][0]*mx + Rw[1][1]*my + Rw[1][2]*mz + tw[1];
    const float pz = Rw[2][0]*mx + Rw[2][1]*my + Rw[2][2]*mz + tw[2];
    zsh[g] = pz;

    float qw = quats[g*4+0], qx = quats[g*4+1], qy = quats[g*4+2], qz = quats[g*4+3];
    const float qn = 1.0f / sqrtf(qw*qw + qx*qx + qy*qy + qz*qz);
    qw *= qn; qx *= qn; qy *= qn; qz *= qn;
    float Rq[3][3];
    Rq[0][0] = 1.f - 2.f*(qy*qy + qz*qz); Rq[0][1] = 2.f*(qx*qy - qw*qz); Rq[0][2] = 2.f*(qx*qz + qw*qy);
    Rq[1][0] = 2.f*(qx*qy + qw*qz); Rq[1][1] = 1.f - 2.f*(qx*qx + qz*qz); Rq[1][2] = 2.f*(qy*qz - qw*qx);
    Rq[2][0] = 2.f*(qx*qz - qw*qy); Rq[2][1] = 2.f*(qy*qz + qw*qx); Rq[2][2] = 1.f - 2.f*(qx*qx + qy*qy);

    const float e0 = expf(scales[g*3+0]);
    const float e1 = expf(scales[g*3+1]);
    const float e2 = expf(scales[g*3+2]);

    float M[3][3];
    #pragma unroll
    for (int i = 0; i < 3; i++) { M[i][0] = Rq[i][0]*e0; M[i][1] = Rq[i][1]*e1; M[i][2] = Rq[i][2]*e2; }
    float c3[3][3];
    #pragma unroll
    for (int i = 0; i < 3; i++)
        #pragma unroll
        for (int k = 0; k < 3; k++)
            c3[i][k] = M[i][0]*M[k][0] + M[i][1]*M[k][1] + M[i][2]*M[k][2];

    float tmp[3][3];
    #pragma unroll
    for (int i = 0; i < 3; i++)
        #pragma unroll
        for (int k = 0; k < 3; k++)
            tmp[i][k] = Rw[i][0]*c3[0][k] + Rw[i][1]*c3[1][k] + Rw[i][2]*c3[2][k];
    float S[3][3];
    #pragma unroll
    for (int i = 0; i < 3; i++)
        #pragma unroll
        for (int l = 0; l < 3; l++)
            S[i][l] = tmp[i][0]*Rw[l][0] + tmp[i][1]*Rw[l][1] + tmp[i][2]*Rw[l][2];

    const float tz = fmaxf(pz, 0.01f);
    const float z1 = 1.0f / tz;
    const float j0 = fx*z1, j2 = -fx*px*z1*z1;
    const float j1 = fy*z1, j3 = -fy*py*z1*z1;

    const float cov00 = j0*j0*S[0][0] + 2.f*j0*j2*S[0][2] + j2*j2*S[2][2];
    const float cov01 = j0*j1*S[0][1] + j0*j3*S[0][2] + j2*j1*S[1][2] + j2*j3*S[2][2];
    const float cov11 = j1*j1*S[1][1] + 2.f*j1*j3*S[1][2] + j3*j3*S[2][2];

    const float a = cov00 + 0.3f;
    const float b = cov01;
    const float c = cov11 + 0.3f;
    const float det = a*c - b*b;
    const float u = fx*px*z1 + cx;
    const float v = fy*py*z1 + cy;
    const bool valid = (pz > 0.01f) && (det > 1e-6f);
    const float inv_det = 1.0f / fmaxf(det, 1e-6f);
    const float Ac = c * inv_det;
    const float Bc = -b * inv_det;
    const float Cc = a * inv_det;
    float op = 1.0f / (1.0f + expf(-opac[g]));
    if (!valid) op = 0.0f;   // zero opacity == culled everywhere

    __syncthreads();
    int rank = 0;
    #pragma unroll 8
    for (int j = 0; j < NG; j++) {
        const float zj = zsh[j];
        rank += (zj < pz) || (zj == pz && j < g);
    }

    float* dst = ws + rank * GF;
    dst[0] = u;  dst[1] = v;  dst[2] = Ac; dst[3] = Bc; dst[4] = Cc;
    dst[5] = op; dst[6] = betas[g];
    dst[7] = colors[g*3+0]; dst[8] = colors[g*3+1]; dst[9] = colors[g*3+2];
}

// ---------------- Kernel 2: strip-culled, chunked compositing ----------------
// Block = 512 threads = 64 pixels (one 64x1 strip) x 8 depth-chunks.
// Grid = 576 strips. LDS ~33 KB -> ~4 blocks/CU ceiling, 2.25 avg.
__global__ __launch_bounds__(512) void render_kernel(
    const float* __restrict__ ws, float* __restrict__ out)
{
    __shared__ __align__(16) float gs[NG * GF];       // 20480 B sorted table
    __shared__ int clist[NG];                          // compacted survivor list
    __shared__ float part[NCHUNK * 64 * 5];            // per-(chunk,pixel) partials
    __shared__ int wcnt[NCHUNK];
    __shared__ int woff[NCHUNK + 1];

    const int tid  = threadIdx.x;
    const int lane = tid & 63;
    const int wv   = tid >> 6;      // wave id == chunk id, 0..7

    // stage the gaussian table (float4-vectorized, coalesced)
    {
        const float4* src = (const float4*)ws;
        float4* dst = (float4*)gs;
        for (int i = tid; i < NG * GF / 4; i += 512) dst[i] = src[i];
    }
    __syncthreads();

    const int strip = blockIdx.x;           // 576 = 192 rows * 3 strips/row
    const int y  = strip / 3;
    const int x0 = (strip % 3) * 64;
    const float fyp = (float)y + 0.5f;
    const float xlo = (float)x0 + 0.5f;
    const float xhi = (float)x0 + 63.5f;

    // ---- exact per-strip cull: max alpha over the strip vs 1/255 ----
    // strip is one row: dy constant; minimize quadratic in dx over [dxlo,dxhi]
    {
        const float* gp = gs + tid * GF;
        const float u = gp[0], v = gp[1], A = gp[2], B = gp[3], C = gp[4];
        const float op = gp[5], bt = gp[6];
        const float dy = fyp - v;
        const float dxlo = xlo - u, dxhi = xhi - u;
        float dxs = -B * dy / fmaxf(A, 1e-12f);        // A > 0 whenever op > 0
        dxs = fminf(fmaxf(dxs, dxlo), dxhi);
        float smin = 0.5f * (A * dxs * dxs + C * dy * dy) + B * dxs * dy;
        smin = fmaxf(smin, 1e-8f);
        const float se = (bt == 1.0f) ? smin : powf(smin, bt);
        const float amax = op * expf(-se);
        const bool keep = amax > (1.0f / 255.0f);

        // order-preserving compaction via per-wave ballot
        const unsigned long long m = __ballot(keep);
        if (lane == 0) wcnt[wv] = __popcll(m);
        __syncthreads();
        if (tid == 0) {
            int s = 0;
            #pragma unroll
            for (int k = 0; k < NCHUNK; k++) { woff[k] = s; s += wcnt[k]; }
            woff[NCHUNK] = s;
        }
        __syncthreads();
        if (keep) {
            const int pos = woff[wv] + __popcll(m & ((1ULL << lane) - 1));
            clist[pos] = tid;
        }
    }
    __syncthreads();

    const int total = woff[NCHUNK];
    // contiguous (order-preserving) split of survivor list across 8 chunks
    const int s = (wv * total) >> 3;
    const int e = ((wv + 1) * total) >> 3;

    const float fxp = (float)(x0 + lane) + 0.5f;
    float T = 1.0f, cr = 0.0f, cg = 0.0f, cb = 0.0f, ac = 0.0f;
    for (int i = s; i < e; i++) {
        const float* gp = gs + clist[i] * GF;   // uniform per wave -> LDS broadcast
        const float dx = fxp - gp[0];
        const float dy = fyp - gp[1];
        float sigma = 0.5f * (gp[2]*dx*dx + gp[4]*dy*dy) + gp[3]*dx*dy;
        sigma = fmaxf(sigma, 1e-8f);
        const float bt = gp[6];
        const float se = (bt == 1.0f) ? sigma : powf(sigma, bt);
        float alpha = gp[5] * expf(-se);
        alpha = fminf(alpha, 0.999f);
        if (!(alpha > (1.0f / 255.0f))) alpha = 0.0f;
        const float w = alpha * T;
        cr += w * gp[7]; cg += w * gp[8]; cb += w * gp[9];
        ac += w;
        T *= 1.0f - alpha;
    }

    float* pp = part + (wv * 64 + lane) * 5;   // stride 5: bank-conflict-free
    pp[0] = cr; pp[1] = cg; pp[2] = cb; pp[3] = ac; pp[4] = T;
    __syncthreads();

    // wave 0 combines the 8 chunks front-to-back
    if (wv == 0) {
        float Tt = 1.0f, r = 0.0f, g = 0.0f, b = 0.0f, a = 0.0f;
        #pragma unroll
        for (int k = 0; k < NCHUNK; k++) {
            const float* pk = part + (k * 64 + lane) * 5;
            r += Tt * pk[0]; g += Tt * pk[1]; b += Tt * pk[2]; a += Tt * pk[3];
            Tt *= pk[4];
        }
        const int pix = y * IMG_W + x0 + lane;
        out[pix * 3 + 0] = r;
        out[pix * 3 + 1] = g;
        out[pix * 3 + 2] = b;
        out[NPIX * 3 + pix] = a;
    }
}

extern "C" void kernel_launch(void* const* d_in, const int* in_sizes, int n_in,
                              void* d_out, int out_size, void* d_ws, size_t ws_size,
                              hipStream_t stream) {
    const float* means  = (const float*)d_in[0];
    const float* quats  = (const float*)d_in[1];
    const float* scales = (const float*)d_in[2];
    const float* opac   = (const float*)d_in[3];
    const float* colors = (const float*)d_in[4];
    const float* betas  = (const float*)d_in[5];
    const float* vm     = (const float*)d_in[6];
    const float* Ks     = (const float*)d_in[7];
    float* ws  = (float*)d_ws;
    float* out = (float*)d_out;

    preprocess_kernel<<<1, NG, 0, stream>>>(means, quats, scales, opac, colors, betas, vm, Ks, ws);
    render_kernel<<<NPIX / 64, 512, 0, stream>>>(ws, out);
}